// Round 1
// baseline (561.115 us; speedup 1.0000x reference)
//
#include <hip/hip_runtime.h>
#include <math.h>

#define T_DIM 4096
#define B_DIM 16
#define P_DIM 512
#define H_DIM 512
#define CHUNKS 64
#define CLEN (T_DIM / CHUNKS)   // 64
#define BP (B_DIM * P_DIM)      // 8192 elems per time-slice
#define BP4 (BP / 4)            // 2048 float4 per time-slice
#define P4 (P_DIM / 4)          // 128

#define BM 128
#define BN 128
#define BK 16

// ---------------------------------------------------------------------------
// Kernel A: discretization. b_bar[p,h] = (expm1(dt*a)/a)*dt * b[p,h]
// also a_bar[p] = exp(dt*a), a_barL[p] = exp(CLEN*dt*a)
// ---------------------------------------------------------------------------
__global__ __launch_bounds__(256) void precompute_kernel(
    const float* __restrict__ log_neg_a,
    const float* __restrict__ b,
    const float* __restrict__ log_dt,
    float* __restrict__ b_bar,
    float* __restrict__ a_bar,
    float* __restrict__ a_barL) {
    int idx = blockIdx.x * blockDim.x + threadIdx.x;
    if (idx >= P_DIM * H_DIM) return;
    int p = idx >> 9;  // / H_DIM
    float dt = expf(log_dt[p]);
    float a  = -expf(log_neg_a[p]);
    float x  = dt * a;
    float scale = (expm1f(x) / a) * dt;
    b_bar[idx] = scale * b[idx];
    if ((idx & (H_DIM - 1)) == 0) {
        a_bar[p]  = expf(x);
        a_barL[p] = expf(x * (float)CLEN);
    }
}

// ---------------------------------------------------------------------------
// Kernel B: fp32 NT GEMM. A = inputs [M=T*B, K=H] row-major,
// Bm = b_bar [N=P, K=H] row-major. C = bu [M, N] -> written into d_out.
// 128x128 tile, 256 threads, 8x8 per thread.
// ---------------------------------------------------------------------------
__global__ __launch_bounds__(256) void gemm_kernel(
    const float* __restrict__ A,
    const float* __restrict__ Bm,
    float* __restrict__ Cout) {
    // As: stride 17 (odd) so inner a-reads (ty varies) hit distinct banks.
    // Bs: stride 20 (16B-aligned rows) so staging can use float4 stores;
    //     inner b-reads are 2-way bank-aliased (free per m136).
    __shared__ float As[BM][BK + 1];
    __shared__ float Bs[BN][BK + 4];
    const int K = H_DIM;
    const int N = P_DIM;

    int tid = threadIdx.x;
    int tx = tid & 15;       // col group
    int ty = tid >> 4;       // row group
    int rowBase = blockIdx.y * BM;
    int colBase = blockIdx.x * BN;

    float acc[8][8];
#pragma unroll
    for (int i = 0; i < 8; ++i)
#pragma unroll
        for (int j = 0; j < 8; ++j) acc[i][j] = 0.f;

    for (int kt = 0; kt < K; kt += BK) {
        // stage: 128 rows x 16 k = 512 float4 per matrix; 2 per thread each
#pragma unroll
        for (int l = 0; l < 2; ++l) {
            int fl = tid * 2 + l;        // 0..511
            int row = fl >> 2;
            int kq = fl & 3;
            float4 av = *reinterpret_cast<const float4*>(
                &A[(size_t)(rowBase + row) * K + kt + kq * 4]);
            As[row][kq * 4 + 0] = av.x;
            As[row][kq * 4 + 1] = av.y;
            As[row][kq * 4 + 2] = av.z;
            As[row][kq * 4 + 3] = av.w;
            float4 bv = *reinterpret_cast<const float4*>(
                &Bm[(size_t)(colBase + row) * K + kt + kq * 4]);
            *reinterpret_cast<float4*>(&Bs[row][kq * 4]) = bv;
        }
        __syncthreads();

#pragma unroll
        for (int k = 0; k < BK; ++k) {
            float af[8], bf[8];
#pragma unroll
            for (int i = 0; i < 8; ++i) af[i] = As[ty * 8 + i][k];
#pragma unroll
            for (int j = 0; j < 8; ++j) bf[j] = Bs[tx + 16 * j][k];
#pragma unroll
            for (int i = 0; i < 8; ++i)
#pragma unroll
                for (int j = 0; j < 8; ++j)
                    acc[i][j] = fmaf(af[i], bf[j], acc[i][j]);
        }
        __syncthreads();
    }

#pragma unroll
    for (int i = 0; i < 8; ++i) {
        size_t r = (size_t)(rowBase + ty * 8 + i);
#pragma unroll
        for (int j = 0; j < 8; ++j) {
            Cout[r * N + colBase + tx + 16 * j] = acc[i][j];
        }
    }
}

// ---------------------------------------------------------------------------
// Kernel C: per-chunk local scan (zero initial state), in place on d_out.
// One thread owns 4 consecutive p for one (chunk, b). Writes chunk carry.
// ---------------------------------------------------------------------------
__global__ __launch_bounds__(256) void scan_local_kernel(
    float4* __restrict__ zio,
    const float4* __restrict__ a_bar4,
    float4* __restrict__ carry) {
    int tid = blockIdx.x * blockDim.x + threadIdx.x;  // CHUNKS*BP4 threads
    int bp4 = tid & (BP4 - 1);
    int c = tid >> 11;  // / BP4
    float4 ab = a_bar4[bp4 & (P4 - 1)];
    size_t base = (size_t)c * CLEN * BP4 + bp4;
    float4 z = make_float4(0.f, 0.f, 0.f, 0.f);
    for (int i = 0; i < CLEN; ++i) {
        size_t off = base + (size_t)i * BP4;
        float4 v = zio[off];
        z.x = fmaf(ab.x, z.x, v.x);
        z.y = fmaf(ab.y, z.y, v.y);
        z.z = fmaf(ab.z, z.z, v.z);
        z.w = fmaf(ab.w, z.w, v.w);
        zio[off] = z;
    }
    carry[tid] = z;
}

// ---------------------------------------------------------------------------
// Kernel D: sequential scan over the 64 chunk carries.
// z_in[c] = state entering chunk c. z_in[c] = aL*z_in[c-1] + carry[c-1].
// ---------------------------------------------------------------------------
__global__ __launch_bounds__(256) void carry_scan_kernel(
    const float4* __restrict__ carry,
    const float4* __restrict__ a_barL4,
    float4* __restrict__ z_in) {
    int bp4 = blockIdx.x * blockDim.x + threadIdx.x;  // 0..BP4-1
    float4 aL = a_barL4[bp4 & (P4 - 1)];
    float4 z = make_float4(0.f, 0.f, 0.f, 0.f);
    for (int c = 0; c < CHUNKS; ++c) {
        z_in[c * BP4 + bp4] = z;
        float4 v = carry[c * BP4 + bp4];
        z.x = fmaf(aL.x, z.x, v.x);
        z.y = fmaf(aL.y, z.y, v.y);
        z.z = fmaf(aL.z, z.z, v.z);
        z.w = fmaf(aL.w, z.w, v.w);
    }
}

// ---------------------------------------------------------------------------
// Kernel E: fixup. z[t0+i] = local[i] + a_bar^{i+1} * z_in[c].  (chunks 1..63)
// ---------------------------------------------------------------------------
__global__ __launch_bounds__(256) void fixup_kernel(
    float4* __restrict__ zio,
    const float4* __restrict__ a_bar4,
    const float4* __restrict__ z_in) {
    int tid = blockIdx.x * blockDim.x + threadIdx.x;  // (CHUNKS-1)*BP4
    int bp4 = tid & (BP4 - 1);
    int c = (tid >> 11) + 1;
    float4 ab = a_bar4[bp4 & (P4 - 1)];
    float4 zin = z_in[c * BP4 + bp4];
    float4 f = ab;
    size_t base = (size_t)c * CLEN * BP4 + bp4;
    for (int i = 0; i < CLEN; ++i) {
        size_t off = base + (size_t)i * BP4;
        float4 v = zio[off];
        v.x = fmaf(f.x, zin.x, v.x);
        v.y = fmaf(f.y, zin.y, v.y);
        v.z = fmaf(f.z, zin.z, v.z);
        v.w = fmaf(f.w, zin.w, v.w);
        zio[off] = v;
        f.x *= ab.x;
        f.y *= ab.y;
        f.z *= ab.z;
        f.w *= ab.w;
    }
}

// ---------------------------------------------------------------------------
extern "C" void kernel_launch(void* const* d_in, const int* in_sizes, int n_in,
                              void* d_out, int out_size, void* d_ws, size_t ws_size,
                              hipStream_t stream) {
    const float* inputs    = (const float*)d_in[0];  // [T, B, H]
    const float* log_neg_a = (const float*)d_in[1];  // [P]
    const float* b         = (const float*)d_in[2];  // [P, H]
    const float* log_dt    = (const float*)d_in[3];  // [P]
    float* out = (float*)d_out;                      // [T, B, P]
    float* ws  = (float*)d_ws;

    // workspace layout (floats); all offsets 16B-aligned
    float* b_bar  = ws;                               // P*H     = 262144
    float* a_bar  = b_bar + P_DIM * H_DIM;            // P       = 512
    float* a_barL = a_bar + P_DIM;                    // P       = 512
    float* carry  = a_barL + P_DIM;                   // C*B*P   = 524288
    float* z_in   = carry + CHUNKS * BP;              // C*B*P   = 524288
    // total ~5.25 MB

    precompute_kernel<<<(P_DIM * H_DIM) / 256, 256, 0, stream>>>(
        log_neg_a, b, log_dt, b_bar, a_bar, a_barL);

    dim3 ggrid(P_DIM / BN, (T_DIM * B_DIM) / BM);  // (4, 512)
    gemm_kernel<<<ggrid, 256, 0, stream>>>(inputs, b_bar, out);

    scan_local_kernel<<<(CHUNKS * BP4) / 256, 256, 0, stream>>>(
        (float4*)out, (const float4*)a_bar, (float4*)carry);

    carry_scan_kernel<<<BP4 / 256, 256, 0, stream>>>(
        (const float4*)carry, (const float4*)a_barL, (float4*)z_in);

    fixup_kernel<<<((CHUNKS - 1) * BP4) / 256, 256, 0, stream>>>(
        (float4*)out, (const float4*)a_bar, (const float4*)z_in);
}

// Round 2
// 193.876 us; speedup vs baseline: 2.8942x; 2.8942x over previous
//
#include <hip/hip_runtime.h>
#include <math.h>

#define T_DIM 4096
#define B_DIM 16
#define P_DIM 512
#define H_DIM 512
#define M_DIM (T_DIM * B_DIM)   // 65536
#define CHUNKS 64
#define CLEN (T_DIM / CHUNKS)   // 64
#define BP (B_DIM * P_DIM)      // 8192
#define BP4 (BP / 4)            // 2048
#define P4 (P_DIM / 4)          // 128

#define KBYTES (H_DIM * 2)      // f16 row bytes = 1024
#define BK 64                   // k per LDS tile

#define SCALE_B 1048576.0f          // 2^20: lifts b_bar out of f16 subnormal range
#define INV_SCALE_B (1.0f / 1048576.0f)

typedef _Float16 f16x8 __attribute__((ext_vector_type(8)));
typedef float f32x4 __attribute__((ext_vector_type(4)));

// generic -> AS1/AS3 casts (CK's double-reinterpret pattern; LDS generic addr
// low 32 bits == LDS offset on gfx9xx)
__device__ __forceinline__ void gload16(const void* g, void* l) {
    __builtin_amdgcn_global_load_lds(
        (const __attribute__((address_space(1))) void*)(uintptr_t)g,
        (__attribute__((address_space(3))) void*)(uint32_t)(uintptr_t)l,
        16, 0, 0);
}

// ---------------------------------------------------------------------------
// Kernel A: discretization. b_bar = (expm1(dt*a)/a)*dt * b ; also f16 scaled
// copy for the MFMA path, and a_bar / a_bar^CLEN.
// ---------------------------------------------------------------------------
__global__ __launch_bounds__(256) void precompute_kernel(
    const float* __restrict__ log_neg_a,
    const float* __restrict__ b,
    const float* __restrict__ log_dt,
    float* __restrict__ b_bar,
    _Float16* __restrict__ b_bar16,
    float* __restrict__ a_bar,
    float* __restrict__ a_barL,
    int write16) {
    int idx = blockIdx.x * blockDim.x + threadIdx.x;
    if (idx >= P_DIM * H_DIM) return;
    int p = idx >> 9;
    float dt = expf(log_dt[p]);
    float a  = -expf(log_neg_a[p]);
    float x  = dt * a;
    float scale = (expm1f(x) / a) * dt;
    float bb = scale * b[idx];
    b_bar[idx] = bb;
    if (write16) b_bar16[idx] = (_Float16)(bb * SCALE_B);
    if ((idx & (H_DIM - 1)) == 0) {
        a_bar[p]  = expf(x);
        a_barL[p] = expf(x * (float)CLEN);
    }
}

// ---------------------------------------------------------------------------
// Kernel A2: fp32 -> f16 conversion of inputs (8 floats / thread).
// ---------------------------------------------------------------------------
__global__ __launch_bounds__(256) void convert_a_kernel(
    const float4* __restrict__ in, f16x8* __restrict__ out) {
    int t = blockIdx.x * blockDim.x + threadIdx.x;   // 0 .. M*H/8-1
    float4 v0 = in[(size_t)t * 2];
    float4 v1 = in[(size_t)t * 2 + 1];
    f16x8 o;
    o[0] = (_Float16)v0.x; o[1] = (_Float16)v0.y;
    o[2] = (_Float16)v0.z; o[3] = (_Float16)v0.w;
    o[4] = (_Float16)v1.x; o[5] = (_Float16)v1.y;
    o[6] = (_Float16)v1.z; o[7] = (_Float16)v1.w;
    out[t] = o;
}

// ---------------------------------------------------------------------------
// Kernel B (fast): f16 MFMA NT GEMM, 128x128 tile, 4 waves, BK=64.
// A16 [M][H] f16 row-major, B16 [P][H] f16 row-major (pre-scaled by 2^20).
// LDS staged via global_load_lds(16B) with linear dest + inverse-swizzled
// global source; reads apply byte ^= (row&7)<<4  (uniform 2-way = free).
// ---------------------------------------------------------------------------
__global__ __launch_bounds__(256) void gemm16_kernel(
    const char* __restrict__ A16,
    const char* __restrict__ B16,
    float* __restrict__ Cout) {
    __shared__ char As[128 * BK * 2];   // 16 KB
    __shared__ char Bs[128 * BK * 2];   // 16 KB

    const int tid  = threadIdx.x;
    const int lane = tid & 63;
    const int wid  = tid >> 6;
    const int rowBase = blockIdx.y * 128;
    const int colBase = blockIdx.x * 128;

    // staging: issue i stages rows [i*32, i*32+32); lane's row = i*32 + tid/8,
    // 16B chunk (tid&7) within the 128B row, inverse-swizzled:
    const int srow = tid >> 3;
    const int scol = ((tid & 7) << 4) ^ ((srow & 7) << 4);
    const char* gA = A16 + (size_t)(rowBase + srow) * KBYTES + scol;
    const char* gB = B16 + (size_t)(colBase + srow) * KBYTES + scol;

    f32x4 acc[4][4];
#pragma unroll
    for (int m2 = 0; m2 < 4; ++m2)
#pragma unroll
        for (int n2 = 0; n2 < 4; ++n2)
            acc[m2][n2] = (f32x4){0.f, 0.f, 0.f, 0.f};

    const int wr = wid >> 1;   // wave's 64x64 quadrant
    const int wc = wid & 1;

    for (int kt = 0; kt < H_DIM / BK; ++kt) {
#pragma unroll
        for (int i = 0; i < 4; ++i) {
            gload16(gA + (size_t)i * 32 * KBYTES, As + (i * 256 + wid * 64) * 16);
            gload16(gB + (size_t)i * 32 * KBYTES, Bs + (i * 256 + wid * 64) * 16);
        }
        gA += BK * 2;   // next 128B k-slab
        gB += BK * 2;
        __syncthreads();   // compiler drains vmcnt before barrier (m97)

#pragma unroll
        for (int kk = 0; kk < 2; ++kk) {
            const int kbyte = kk * 64 + ((lane >> 4) << 4);
            f16x8 af[4], bf[4];
#pragma unroll
            for (int m2 = 0; m2 < 4; ++m2) {
                int row = wr * 64 + m2 * 16 + (lane & 15);
                af[m2] = *(const f16x8*)(As + row * 128 + (kbyte ^ ((row & 7) << 4)));
            }
#pragma unroll
            for (int n2 = 0; n2 < 4; ++n2) {
                int col = wc * 64 + n2 * 16 + (lane & 15);
                bf[n2] = *(const f16x8*)(Bs + col * 128 + (kbyte ^ ((col & 7) << 4)));
            }
#pragma unroll
            for (int m2 = 0; m2 < 4; ++m2)
#pragma unroll
                for (int n2 = 0; n2 < 4; ++n2)
                    acc[m2][n2] = __builtin_amdgcn_mfma_f32_16x16x32_f16(
                        af[m2], bf[n2], acc[m2][n2], 0, 0, 0);
        }
        __syncthreads();
    }

    // epilogue: C/D layout col=lane&15, row=(lane>>4)*4+reg (m89)
#pragma unroll
    for (int m2 = 0; m2 < 4; ++m2) {
#pragma unroll
        for (int r = 0; r < 4; ++r) {
            size_t row = (size_t)(rowBase + wr * 64 + m2 * 16 + (lane >> 4) * 4 + r);
            float* po = Cout + row * P_DIM + colBase + wc * 64 + (lane & 15);
#pragma unroll
            for (int n2 = 0; n2 < 4; ++n2)
                po[n2 * 16] = acc[m2][n2][r] * INV_SCALE_B;
        }
    }
}

// ---------------------------------------------------------------------------
// Kernel B (fallback): fp32 NT GEMM (proven R1 path), used if ws too small.
// ---------------------------------------------------------------------------
#define BM 128
#define BN 128
#define BKF 16
__global__ __launch_bounds__(256) void gemm_kernel(
    const float* __restrict__ A,
    const float* __restrict__ Bm,
    float* __restrict__ Cout) {
    __shared__ float As[BM][BKF + 1];
    __shared__ float Bs[BN][BKF + 4];
    const int K = H_DIM;
    const int N = P_DIM;
    int tid = threadIdx.x;
    int tx = tid & 15;
    int ty = tid >> 4;
    int rowBase = blockIdx.y * BM;
    int colBase = blockIdx.x * BN;
    float acc[8][8];
#pragma unroll
    for (int i = 0; i < 8; ++i)
#pragma unroll
        for (int j = 0; j < 8; ++j) acc[i][j] = 0.f;
    for (int kt = 0; kt < K; kt += BKF) {
#pragma unroll
        for (int l = 0; l < 2; ++l) {
            int fl = tid * 2 + l;
            int row = fl >> 2;
            int kq = fl & 3;
            float4 av = *reinterpret_cast<const float4*>(
                &A[(size_t)(rowBase + row) * K + kt + kq * 4]);
            As[row][kq * 4 + 0] = av.x;
            As[row][kq * 4 + 1] = av.y;
            As[row][kq * 4 + 2] = av.z;
            As[row][kq * 4 + 3] = av.w;
            float4 bv = *reinterpret_cast<const float4*>(
                &Bm[(size_t)(colBase + row) * K + kt + kq * 4]);
            *reinterpret_cast<float4*>(&Bs[row][kq * 4]) = bv;
        }
        __syncthreads();
#pragma unroll
        for (int k = 0; k < BKF; ++k) {
            float af[8], bf[8];
#pragma unroll
            for (int i = 0; i < 8; ++i) af[i] = As[ty * 8 + i][k];
#pragma unroll
            for (int j = 0; j < 8; ++j) bf[j] = Bs[tx + 16 * j][k];
#pragma unroll
            for (int i = 0; i < 8; ++i)
#pragma unroll
                for (int j = 0; j < 8; ++j)
                    acc[i][j] = fmaf(af[i], bf[j], acc[i][j]);
        }
        __syncthreads();
    }
#pragma unroll
    for (int i = 0; i < 8; ++i) {
        size_t r = (size_t)(rowBase + ty * 8 + i);
#pragma unroll
        for (int j = 0; j < 8; ++j)
            Cout[r * N + colBase + tx + 16 * j] = acc[i][j];
    }
}

// ---------------------------------------------------------------------------
// Kernel C: per-chunk local scan (zero init), in place on d_out.
// ---------------------------------------------------------------------------
__global__ __launch_bounds__(256) void scan_local_kernel(
    float4* __restrict__ zio,
    const float4* __restrict__ a_bar4,
    float4* __restrict__ carry) {
    int tid = blockIdx.x * blockDim.x + threadIdx.x;
    int bp4 = tid & (BP4 - 1);
    int c = tid >> 11;
    float4 ab = a_bar4[bp4 & (P4 - 1)];
    size_t base = (size_t)c * CLEN * BP4 + bp4;
    float4 z = make_float4(0.f, 0.f, 0.f, 0.f);
    for (int i = 0; i < CLEN; ++i) {
        size_t off = base + (size_t)i * BP4;
        float4 v = zio[off];
        z.x = fmaf(ab.x, z.x, v.x);
        z.y = fmaf(ab.y, z.y, v.y);
        z.z = fmaf(ab.z, z.z, v.z);
        z.w = fmaf(ab.w, z.w, v.w);
        zio[off] = z;
    }
    carry[tid] = z;
}

// ---------------------------------------------------------------------------
// Kernel D: sequential scan over chunk carries.
// ---------------------------------------------------------------------------
__global__ __launch_bounds__(256) void carry_scan_kernel(
    const float4* __restrict__ carry,
    const float4* __restrict__ a_barL4,
    float4* __restrict__ z_in) {
    int bp4 = blockIdx.x * blockDim.x + threadIdx.x;
    float4 aL = a_barL4[bp4 & (P4 - 1)];
    float4 z = make_float4(0.f, 0.f, 0.f, 0.f);
    for (int c = 0; c < CHUNKS; ++c) {
        z_in[c * BP4 + bp4] = z;
        float4 v = carry[c * BP4 + bp4];
        z.x = fmaf(aL.x, z.x, v.x);
        z.y = fmaf(aL.y, z.y, v.y);
        z.z = fmaf(aL.z, z.z, v.z);
        z.w = fmaf(aL.w, z.w, v.w);
    }
}

// ---------------------------------------------------------------------------
// Kernel E: fixup. z[t0+i] += a_bar^{i+1} * z_in[c]  (chunks 1..63)
// ---------------------------------------------------------------------------
__global__ __launch_bounds__(256) void fixup_kernel(
    float4* __restrict__ zio,
    const float4* __restrict__ a_bar4,
    const float4* __restrict__ z_in) {
    int tid = blockIdx.x * blockDim.x + threadIdx.x;
    int bp4 = tid & (BP4 - 1);
    int c = (tid >> 11) + 1;
    float4 ab = a_bar4[bp4 & (P4 - 1)];
    float4 zin = z_in[c * BP4 + bp4];
    float4 f = ab;
    size_t base = (size_t)c * CLEN * BP4 + bp4;
    for (int i = 0; i < CLEN; ++i) {
        size_t off = base + (size_t)i * BP4;
        float4 v = zio[off];
        v.x = fmaf(f.x, zin.x, v.x);
        v.y = fmaf(f.y, zin.y, v.y);
        v.z = fmaf(f.z, zin.z, v.z);
        v.w = fmaf(f.w, zin.w, v.w);
        zio[off] = v;
        f.x *= ab.x;
        f.y *= ab.y;
        f.z *= ab.z;
        f.w *= ab.w;
    }
}

// ---------------------------------------------------------------------------
extern "C" void kernel_launch(void* const* d_in, const int* in_sizes, int n_in,
                              void* d_out, int out_size, void* d_ws, size_t ws_size,
                              hipStream_t stream) {
    const float* inputs    = (const float*)d_in[0];  // [T, B, H]
    const float* log_neg_a = (const float*)d_in[1];  // [P]
    const float* b         = (const float*)d_in[2];  // [P, H]
    const float* log_dt    = (const float*)d_in[3];  // [P]
    float* out = (float*)d_out;                      // [T, B, P]
    float* ws  = (float*)d_ws;

    // workspace layout (float units)
    float* b_bar  = ws;                               // 262144
    float* a_bar  = b_bar + P_DIM * H_DIM;            // 512
    float* a_barL = a_bar + P_DIM;                    // 512
    float* carry  = a_barL + P_DIM;                   // 524288
    float* z_in   = carry + CHUNKS * BP;              // 524288
    float* tail   = z_in + CHUNKS * BP;
    _Float16* b_bar16 = (_Float16*)tail;              // 262144 f16
    _Float16* A16     = b_bar16 + P_DIM * H_DIM;      // 33554432 f16

    size_t ws_need = ((char*)(A16 + (size_t)M_DIM * H_DIM)) - (char*)ws;
    int fast = (ws_size >= ws_need);

    precompute_kernel<<<(P_DIM * H_DIM) / 256, 256, 0, stream>>>(
        log_neg_a, b, log_dt, b_bar, b_bar16, a_bar, a_barL, fast);

    if (fast) {
        convert_a_kernel<<<(M_DIM * H_DIM / 8) / 256, 256, 0, stream>>>(
            (const float4*)inputs, (f16x8*)A16);
        dim3 ggrid(P_DIM / 128, M_DIM / 128);  // (4, 512)
        gemm16_kernel<<<ggrid, 256, 0, stream>>>(
            (const char*)A16, (const char*)b_bar16, out);
    } else {
        dim3 ggrid(P_DIM / BN, M_DIM / BM);
        gemm_kernel<<<ggrid, 256, 0, stream>>>(inputs, b_bar, out);
    }

    scan_local_kernel<<<(CHUNKS * BP4) / 256, 256, 0, stream>>>(
        (float4*)out, (const float4*)a_bar, (float4*)carry);

    carry_scan_kernel<<<BP4 / 256, 256, 0, stream>>>(
        (const float4*)carry, (const float4*)a_barL, (float4*)z_in);

    fixup_kernel<<<((CHUNKS - 1) * BP4) / 256, 256, 0, stream>>>(
        (float4*)out, (const float4*)a_bar, (float4*)z_in);
}